// Round 2
// baseline (504.042 us; speedup 1.0000x reference)
//
#include <hip/hip_runtime.h>

// Problem constants
#define T_LEN 8192
#define DMODEL 1536
#define NH 16
#define NKV 4
#define HD 96
#define KVDIM (NKV * HD)   // 384
#define W2 256             // WINDOW/2
#define NFREQ 48           // HD/2
#define NGB 32             // global-attention split-k blocks per head
#define NPROJ 3072         // total projection output columns (q + k + v + kg + vg)

static constexpr float SCALE = 0.10206207261596577f; // 1/sqrt(96)

typedef float f32x4 __attribute__((ext_vector_type(4)));
typedef short short8 __attribute__((ext_vector_type(8)));
typedef unsigned short ushort;

__device__ __forceinline__ ushort f2bf(float f) {
  unsigned int x = __float_as_uint(f);
  return (ushort)((x + 0x7FFFu + ((x >> 16) & 1u)) >> 16);
}
__device__ __forceinline__ float bf2f(ushort u) {
  return __uint_as_float((unsigned int)u << 16);
}
__device__ __forceinline__ void load_lds16(const void* g, void* l) {
  __builtin_amdgcn_global_load_lds(
      (const __attribute__((address_space(1))) void*)g,
      (__attribute__((address_space(3))) void*)l, 16, 0, 0);
}

// ---------------------------------------------------------------------------
// Elementwise fp32 -> bf16
// ---------------------------------------------------------------------------
__global__ __launch_bounds__(256) void convert_bf16(
    const float* __restrict__ in, ushort* __restrict__ out, int n4) {
  const int i = blockIdx.x * 256 + threadIdx.x;
  if (i >= n4) return;
  const f32x4 v = *(const f32x4*)&in[i * 4];
  ushort o[4] = {f2bf(v[0]), f2bf(v[1]), f2bf(v[2]), f2bf(v[3])};
  *(unsigned long long*)&out[i * 4] =
      (unsigned long long)o[0] | ((unsigned long long)o[1] << 16) |
      ((unsigned long long)o[2] << 32) | ((unsigned long long)o[3] << 48);
}

// ---------------------------------------------------------------------------
// W[K][N] fp32 -> Wt[N][K] bf16 (single)
// ---------------------------------------------------------------------------
__global__ __launch_bounds__(256) void transpose_bf16(
    const float* __restrict__ W, ushort* __restrict__ Wt, int K, int N) {
  __shared__ ushort tile[32][33];
  const int tx = threadIdx.x & 31;
  const int ty = threadIdx.x >> 5;
  const int n0 = blockIdx.x * 32;
  const int k0 = blockIdx.y * 32;
#pragma unroll
  for (int i = 0; i < 32; i += 8)
    tile[tx][ty + i] = f2bf(W[(size_t)(k0 + ty + i) * N + n0 + tx]);
  __syncthreads();
#pragma unroll
  for (int i = 0; i < 32; i += 8)
    Wt[(size_t)(n0 + ty + i) * K + k0 + tx] = tile[ty + i][tx];
}

// Batched version for the 4 KV weights (z selects source).
__global__ __launch_bounds__(256) void transpose_bf16_kv4(
    const float* __restrict__ Wk, const float* __restrict__ Wv,
    const float* __restrict__ Wkg, const float* __restrict__ Wvg,
    ushort* __restrict__ Wt) {
  const int z = blockIdx.z;
  const float* W = (z == 0) ? Wk : (z == 1) ? Wv : (z == 2) ? Wkg : Wvg;
  ushort* dst = Wt + (size_t)z * KVDIM * DMODEL;
  __shared__ ushort tile[32][33];
  const int tx = threadIdx.x & 31;
  const int ty = threadIdx.x >> 5;
  const int n0 = blockIdx.x * 32;
  const int k0 = blockIdx.y * 32;
#pragma unroll
  for (int i = 0; i < 32; i += 8)
    tile[tx][ty + i] = f2bf(W[(size_t)(k0 + ty + i) * KVDIM + n0 + tx]);
  __syncthreads();
#pragma unroll
  for (int i = 0; i < 32; i += 8)
    dst[(size_t)(n0 + ty + i) * DMODEL + k0 + tx] = tile[ty + i][tx];
}

// ---------------------------------------------------------------------------
// bf16 [T][KVDIM] -> bf16 [KVDIM][T] (V pre-transpose for local attn)
// ---------------------------------------------------------------------------
__global__ __launch_bounds__(256) void transpose_u16(
    const ushort* __restrict__ in, ushort* __restrict__ out) {
  __shared__ ushort tile[32][33];
  const int tx = threadIdx.x & 31;
  const int ty = threadIdx.x >> 5;
  const int c0 = blockIdx.x * 32;   // dim
  const int r0 = blockIdx.y * 32;   // t
#pragma unroll
  for (int i = 0; i < 32; i += 8)
    tile[ty + i][tx] = in[(size_t)(r0 + ty + i) * KVDIM + c0 + tx];
  __syncthreads();
#pragma unroll
  for (int i = 0; i < 32; i += 8)
    out[(size_t)(c0 + ty + i) * T_LEN + r0 + tx] = tile[tx][ty + i];
}

// ---------------------------------------------------------------------------
// 256x256 deep-pipelined bf16 GEMM core (K = 1536 = 48 tiles of BK=32).
// 8 waves (2M x 4N), 4-deep LDS ring buffer (4 x 32KB = 128KB).
// T3 recipe order: STAGE(t+3) FIRST, then ds_read+MFMA, then counted
// WAITV + raw s_barrier at the END of the body. NO sched_barrier(0) --
// the compiler's list scheduler interleaves VMEM issue / ds_read / MFMA
// (pinning it was the Round-1 regression, cf. m141).
//
// LDS tile layout: [256 rows][32 bf16] = 64B rows; 16B-chunk index
// XOR-swizzled with (row>>1)&3 on the pre-swizzled GLOBAL source
// (global_load_lds dest stays linear) and on the ds_read address ->
// fragment reads are fully conflict-free (verified: conflicts ~0).
//
// Race-freedom: body t stages slot (t+3)&3 == (t-1)&3, which every wave
// finished reading before the barrier at the end of body t-1. Each wave
// confirms its own tile-(t+1) loads via WAITV before the barrier, so
// after the barrier all waves' loads for t+1 are visible in LDS.
// ---------------------------------------------------------------------------
#define WAITV(N) asm volatile("s_waitcnt vmcnt(" #N ")" ::: "memory")

#define STAGE(buf)                                                            \
  { char* db_ = lds + (buf) * 32768 + w * 1024;                               \
    load_lds16(sA0, db_);                                                     \
    load_lds16(sA1, db_ + 8192);                                              \
    load_lds16(sB0, db_ + 16384);                                             \
    load_lds16(sB1, db_ + 24576);                                             \
    sA0 += 32; sA1 += 32; sB0 += 32; sB1 += 32; }

#define COMPUTE32(t)                                                          \
  { const char* Ab_ = lds + ((t) & 3) * 32768;                                \
    const char* Bb_ = Ab_ + 16384;                                            \
    short8 bf_[4];                                                            \
    _Pragma("unroll") for (int nf = 0; nf < 4; ++nf)                          \
        bf_[nf] = *(const short8*)(Bb_ + boff + nf * 1024);                   \
    _Pragma("unroll") for (int mh = 0; mh < 2; ++mh) {                        \
      short8 af_[4];                                                          \
      _Pragma("unroll") for (int mf = 0; mf < 4; ++mf)                        \
          af_[mf] = *(const short8*)(Ab_ + aoff + (mh * 4 + mf) * 1024);      \
      __builtin_amdgcn_s_setprio(1);                                          \
      _Pragma("unroll") for (int mf = 0; mf < 4; ++mf)                        \
          _Pragma("unroll") for (int nf = 0; nf < 4; ++nf)                    \
              acc[mh * 4 + mf][nf] = __builtin_amdgcn_mfma_f32_16x16x32_bf16( \
                  af_[mf], bf_[nf], acc[mh * 4 + mf][nf], 0, 0, 0);           \
      __builtin_amdgcn_s_setprio(0);                                          \
    }                                                                         \
  }

#define GEMM256_PRE(APTR, BPTR, GXDIM)                                        \
  __shared__ __align__(16) char lds[131072];                                  \
  const int tid = threadIdx.x;                                                \
  const int w = tid >> 6;                                                     \
  const int lane = tid & 63;                                                  \
  const int lo = lane & 15;                                                   \
  const int quad = lane >> 4;                                                 \
  const int wm = w >> 2;                                                      \
  const int wn = w & 3;                                                       \
  /* T1: bijective XCD swizzle (nwg % 8 == 0 for both call sites) */          \
  const int lid_ = (int)blockIdx.y * (GXDIM) + (int)blockIdx.x;               \
  const int per_ = ((GXDIM) * (int)gridDim.y) >> 3;                           \
  const int nl_ = (lid_ & 7) * per_ + (lid_ >> 3);                            \
  const int bx_ = nl_ % (GXDIM);                                              \
  const int by_ = nl_ / (GXDIM);                                              \
  const int m0 = by_ * 256;                                                   \
  const int n0 = bx_ * 256;                                                   \
  /* fragment-read swizzle: chunk ^= (row>>1)&3; (row>>1)&3 == (lo>>1)&3 */   \
  const int swz = (quad ^ ((lo >> 1) & 3)) << 4;                              \
  const int aoff = (wm * 128 + lo) * 64 + swz;                                \
  const int boff = (wn * 64 + lo) * 64 + swz;                                 \
  /* staging: idx in [0,1024) -> row = idx>>2, lds-chunk = idx&3; source */   \
  /* element chunk = ldschunk ^ ((row>>1)&3) (involution)               */    \
  const int rA0 = tid >> 2, cp0 = tid & 3;                                    \
  const int rA1 = 128 + rA0;                                                  \
  const int lc0 = cp0 ^ ((rA0 >> 1) & 3);                                     \
  const int lc1 = cp0 ^ ((rA1 >> 1) & 3);                                     \
  const ushort* sA0 = (APTR) + (size_t)(m0 + rA0) * 1536 + lc0 * 8;           \
  const ushort* sA1 = (APTR) + (size_t)(m0 + rA1) * 1536 + lc1 * 8;           \
  const ushort* sB0 = (BPTR) + (size_t)(n0 + rA0) * 1536 + lc0 * 8;           \
  const ushort* sB1 = (BPTR) + (size_t)(n0 + rA1) * 1536 + lc1 * 8;           \
  f32x4 acc[8][4];                                                            \
  _Pragma("unroll") for (int i = 0; i < 8; ++i)                               \
      _Pragma("unroll") for (int j = 0; j < 4; ++j)                           \
          acc[i][j] = {0.f, 0.f, 0.f, 0.f};

#define GEMM256_LOOP()                                                        \
  STAGE(0) STAGE(1) STAGE(2)                                                  \
  WAITV(8);                                                                   \
  __builtin_amdgcn_s_barrier();                                               \
  _Pragma("unroll 1") for (int t = 0; t < 45; ++t) {                          \
    STAGE((t + 3) & 3)                                                        \
    COMPUTE32(t)                                                              \
    WAITV(8);                                                                 \
    __builtin_amdgcn_s_barrier();                                             \
  }                                                                           \
  COMPUTE32(45)                                                               \
  WAITV(4);                                                                   \
  __builtin_amdgcn_s_barrier();                                               \
  COMPUTE32(46)                                                               \
  WAITV(0);                                                                   \
  __builtin_amdgcn_s_barrier();                                               \
  COMPUTE32(47)

// ---------------------------------------------------------------------------
// Unified projection GEMM: A[8192][1536] @ Wall[3072][1536]^T, 256^2 tiles.
// Column sections: [0,1536) q (rope, bf16) | [1536,1920) k (rope, bf16) |
// [1920,2304) v (bf16) | [2304,2688) kg (rope, f32) | [2688,3072) vg (f32).
// Sections are resolved PER COLUMN (256-wide blocks straddle boundaries).
// ---------------------------------------------------------------------------
__global__ __launch_bounds__(512, 1) void gemm_proj256(
    const ushort* __restrict__ A, const ushort* __restrict__ Wall,
    ushort* __restrict__ q_bf, ushort* __restrict__ k_bf,
    ushort* __restrict__ v_bf, float* __restrict__ kg,
    float* __restrict__ vg, const float* __restrict__ cosf,
    const float* __restrict__ sinf, const int* __restrict__ pid) {
  GEMM256_PRE(A, Wall, 12)
  GEMM256_LOOP()

  // ---- epilogue: fused RoPE + dtype routing ----
  __syncthreads();  // all LDS reads of the K-loop done; reuse lds
  const int xb = bx_;
  const bool blkRope = (xb <= 7) || (xb == 9) || (xb == 10);
  int* PidS = (int*)lds;                       // [256]
  unsigned int* CoefS = (unsigned int*)(lds + 1024);  // [256][48] cos|sin bf16
  if (blkRope) {
    if (tid < 256) PidS[tid] = pid[m0 + tid];
    __syncthreads();
#pragma unroll
    for (int j = 0; j < 24; ++j) {
      const int idx = j * 512 + tid;          // 0..12287
      const int rr = idx / 48;
      const int ff = idx - rr * 48;
      const int pos = PidS[rr];
      CoefS[idx] = (unsigned int)f2bf(cosf[(size_t)pos * NFREQ + ff]) |
                   ((unsigned int)f2bf(sinf[(size_t)pos * NFREQ + ff]) << 16);
    }
    __syncthreads();
  }

#pragma unroll
  for (int nf = 0; nf < 4; ++nf) {
    const int cc = n0 + wn * 64 + nf * 16 + lo;
    int sec, cbase;
    if (cc < 1536)      { sec = 0; cbase = 0; }
    else if (cc < 1920) { sec = 1; cbase = 1536; }
    else if (cc < 2304) { sec = 2; cbase = 1920; }
    else if (cc < 2688) { sec = 3; cbase = 2304; }
    else                { sec = 4; cbase = 2688; }
    const int col = cc - cbase;
    const int d = col % HD;
    const int fi = d >> 1;
    const bool doRope = (sec == 0) || (sec == 1) || (sec == 3);
#pragma unroll
    for (int mf = 0; mf < 8; ++mf) {
      const int lr0 = wm * 128 + mf * 16 + quad * 4;
#pragma unroll
      for (int r = 0; r < 4; ++r) {
        const int lr = lr0 + r;
        float v = acc[mf][nf][r];
        const float pe = __shfl_xor(v, 1);   // partner column (col^1)
        if (doRope) {
          const unsigned int pk = CoefS[lr * 48 + fi];
          const float co = bf2f((ushort)(pk & 0xFFFF));
          const float si = bf2f((ushort)(pk >> 16));
          v = (d & 1) ? fmaf(pe, si, v * co) : fmaf(v, co, -pe * si);
        }
        const int trow = m0 + lr;
        if (sec == 0)      q_bf[(size_t)trow * DMODEL + col] = f2bf(v);
        else if (sec == 1) k_bf[(size_t)trow * KVDIM + col] = f2bf(v);
        else if (sec == 2) v_bf[(size_t)trow * KVDIM + col] = f2bf(v);
        else if (sec == 3) kg[(size_t)trow * KVDIM + col] = v;
        else               vg[(size_t)trow * KVDIM + col] = v;
      }
    }
  }
}

// ---------------------------------------------------------------------------
// Output projection GEMM: attn[8192][1536] @ Wo_t[1536][1536]^T -> f32
// ---------------------------------------------------------------------------
__global__ __launch_bounds__(512, 1) void gemm_out256(
    const ushort* __restrict__ A, const ushort* __restrict__ Bt,
    float* __restrict__ C) {
  GEMM256_PRE(A, Bt, 6)
  GEMM256_LOOP()
#pragma unroll
  for (int mf = 0; mf < 8; ++mf) {
    const int r0 = m0 + wm * 128 + mf * 16 + quad * 4;
#pragma unroll
    for (int nf = 0; nf < 4; ++nf) {
      const int cc = n0 + wn * 64 + nf * 16 + lo;
#pragma unroll
      for (int r = 0; r < 4; ++r)
        C[(size_t)(r0 + r) * DMODEL + cc] = acc[mf][nf][r];
    }
  }
}

// ---------------------------------------------------------------------------
// qg row 0: zero + split-k atomics
// ---------------------------------------------------------------------------
__global__ void qg0_zero(float* __restrict__ qg0) {
  qg0[blockIdx.x * 256 + threadIdx.x] = 0.f;
}
__global__ __launch_bounds__(256) void qg0_split(
    const float* __restrict__ x, const float* __restrict__ W,
    float* __restrict__ qg0) {
  const int j = blockIdx.x * 256 + threadIdx.x;
  const int k0 = blockIdx.y * 128;
  float acc = 0.f;
#pragma unroll 8
  for (int k = k0; k < k0 + 128; ++k)
    acc = fmaf(x[k], W[(size_t)k * DMODEL + j], acc);
  atomicAdd(&qg0[j], acc);
}

// ---------------------------------------------------------------------------
// Local attention v4: MFMA bf16 flash tiles; V staged from pre-transposed
// Vt_g[KVDIM][T] via global_load_lds.
// ---------------------------------------------------------------------------
__global__ __launch_bounds__(256) void local_attn_v4(
    const ushort* __restrict__ qbf, const ushort* __restrict__ kbf,
    const ushort* __restrict__ vtg, const float* __restrict__ kg,
    const float* __restrict__ vg, ushort* __restrict__ obf) {
  __shared__ ushort Qb[3 * 64 * 32];
  __shared__ ushort Kb[3 * 64 * 32];
  __shared__ ushort Vt[2 * 96 * 32];   // panel kp: [96 dims][32 keys]
  __shared__ ushort Pb[4][2 * 16 * 32];
  __shared__ float Kg0[HD];
  __shared__ float Vg0[HD];

  const int t0 = blockIdx.x * 64;
  const int h  = blockIdx.y;
  const int kh = h >> 2;
  const int tid = threadIdx.x;
  const int w    = tid >> 6;
  const int lane = tid & 63;
  const int lo   = lane & 15;
  const int quad = lane >> 4;

  {
    const int rem = w * 64 + lane;
    const int row = rem >> 2;
    const int sub = (rem & 3) * 8;
#pragma unroll
    for (int j = 0; j < 3; ++j) {
      load_lds16(qbf + (size_t)(t0 + row) * DMODEL + h * HD + j * 32 + sub,
                 (char*)Qb + (j * 256 + w * 64) * 16);
    }
  }
  if (tid < HD) {
    Kg0[tid] = kg[kh * HD + tid];   // row 0 (rope at pos 0 = identity)
    Vg0[tid] = vg[kh * HD + tid];
  }

  f32x4 O[6];
#pragma unroll
  for (int i = 0; i < 6; ++i) O[i] = {0.f, 0.f, 0.f, 0.f};
  float m_run[4], l_run[4];
#pragma unroll
  for (int r = 0; r < 4; ++r) { m_run[r] = -1e30f; l_run[r] = 0.f; }

  __syncthreads();

  for (int ti = 0; ti < 5; ++ti) {
    const int kb = t0 - W2 + ti * 64;
    if (kb < 0) continue;

    {
      const int rem = w * 64 + lane;
      const int row = rem >> 2;
      const int sub = (rem & 3) * 8;
#pragma unroll
      for (int j = 0; j < 3; ++j) {
        load_lds16(kbf + (size_t)(kb + row) * KVDIM + kh * HD + j * 32 + sub,
                   (char*)Kb + (j * 256 + w * 64) * 16);
      }
#pragma unroll
      for (int j = 0; j < 3; ++j) {
        const int cc = j * 256 + w * 64 + lane;
        const int half = cc / 384;
        const int rm2 = cc - half * 384;
        const int dd = rm2 >> 2;
        const int sb = (rm2 & 3) * 8;
        load_lds16(vtg + (size_t)(kh * HD + dd) * T_LEN + kb + half * 32 + sb,
                   (char*)Vt + (j * 256 + w * 64) * 16);
      }
    }
    __syncthreads();

    short8 af[3];
#pragma unroll
    for (int p = 0; p < 3; ++p)
      af[p] = *(const short8*)&Qb[p * 2048 + (w * 16 + lo) * 32 + quad * 8];
    f32x4 s4[4];
#pragma unroll
    for (int nt = 0; nt < 4; ++nt) s4[nt] = {0.f, 0.f, 0.f, 0.f};
#pragma unroll
    for (int nt = 0; nt < 4; ++nt)
#pragma unroll
      for (int p = 0; p < 3; ++p) {
        const short8 bf8 =
            *(const short8*)&Kb[p * 2048 + (nt * 16 + lo) * 32 + quad * 8];
        s4[nt] = __builtin_amdgcn_mfma_f32_16x16x32_bf16(af[p], bf8, s4[nt], 0, 0, 0);
      }

    float alpha[4];
#pragma unroll
    for (int r = 0; r < 4; ++r) {
      const int tq = t0 + w * 16 + quad * 4 + r;
      float sv[4], rm = -1e30f;
#pragma unroll
      for (int nt = 0; nt < 4; ++nt) {
        const int p = kb + nt * 16 + lo;
        const bool ok = (p >= 1) && (p <= tq) && (p + W2 >= tq);
        sv[nt] = ok ? s4[nt][r] * SCALE : -1e30f;
        rm = fmaxf(rm, sv[nt]);
      }
#pragma unroll
      for (int mo = 1; mo < 16; mo <<= 1) rm = fmaxf(rm, __shfl_xor(rm, mo));
      const float m_new = fmaxf(m_run[r], rm);
      float psum = 0.f;
#pragma unroll
      for (int nt = 0; nt < 4; ++nt) {
        const float pv = (sv[nt] > -1e29f) ? __expf(sv[nt] - m_new) : 0.f;
        Pb[w][(nt >> 1) * 512 + (quad * 4 + r) * 32 + (nt & 1) * 16 + lo] = f2bf(pv);
        psum += pv;
      }
#pragma unroll
      for (int mo = 1; mo < 16; mo <<= 1) psum += __shfl_xor(psum, mo);
      alpha[r] = __expf(m_run[r] - m_new);
      l_run[r] = l_run[r] * alpha[r] + psum;
      m_run[r] = m_new;
    }

#pragma unroll
    for (int nt6 = 0; nt6 < 6; ++nt6)
#pragma unroll
      for (int r = 0; r < 4; ++r) O[nt6][r] *= alpha[r];

    short8 pa[2];
#pragma unroll
    for (int kp = 0; kp < 2; ++kp)
      pa[kp] = *(const short8*)&Pb[w][kp * 512 + lo * 32 + quad * 8];
#pragma unroll
    for (int nt6 = 0; nt6 < 6; ++nt6)
#pragma unroll
      for (int kp = 0; kp < 2; ++kp) {
        const short8 vb8 =
            *(const short8*)&Vt[kp * 3072 + (nt6 * 16 + lo) * 32 + quad * 8];
        O[nt6] = __builtin_amdgcn_mfma_f32_16x16x32_bf16(pa[kp], vb8, O[nt6], 0, 0, 0);
      }
    __syncthreads();
  }

  float sg[4];
#pragma unroll
  for (int r = 0; r < 4; ++r) {
    const int row = w * 16 + quad * 4 + r;
    float part = 0.f;
#pragma unroll
    for (int i = 0; i < 6; ++i) {
      const int d = lo * 6 + i;
      part += bf2f(Qb[(d >> 5) * 2048 + row * 32 + (d & 31)]) * Kg0[d];
    }
#pragma unroll
    for (int mo = 1; mo < 16; mo <<= 1) part += __shfl_xor(part, mo);
    sg[r] = part * SCALE;
  }
#pragma unroll
  for (int r = 0; r < 4; ++r) {
    const float m_new = fmaxf(m_run[r], sg[r]);
    const float al = __expf(m_run[r] - m_new);
    const float pg = __expf(sg[r] - m_new);
    const float inv = 1.0f / (l_run[r] * al + pg);
    ushort* dst = obf + (size_t)(t0 + w * 16 + quad * 4 + r) * DMODEL + h * HD;
#pragma unroll
    for (int nt6 = 0; nt6 < 6; ++nt6) {
      const int d = nt6 * 16 + lo;
      dst[d] = f2bf((O[nt6][r] * al + pg * Vg0[d]) * inv);
    }
  }
}

// ---------------------------------------------------------------------------
// Global row, split-k partials: grid (NH, NGB); 256 keys per block.
// ---------------------------------------------------------------------------
__global__ __launch_bounds__(256) void global_attn_part(
    const float* __restrict__ qg0, const float* __restrict__ kg,
    const float* __restrict__ vg, float* __restrict__ gM,
    float* __restrict__ gL, float* __restrict__ gO) {
  const int h = blockIdx.x;
  const int g = blockIdx.y;
  const int kh = h >> 2;
  const int tid = threadIdx.x;
  const int wv = tid >> 6;
  __shared__ float q[HD];
  __shared__ float sp[256];
  __shared__ float red[4];
  __shared__ float od[2][HD];

  if (tid < HD) q[tid] = qg0[h * HD + tid];
  __syncthreads();

  const int key = g * 256 + tid;
  const float* kp = kg + (size_t)key * KVDIM + kh * HD;
  float d = 0.f;
#pragma unroll
  for (int j = 0; j < 24; ++j) {
    const f32x4 kv = *(const f32x4*)(kp + j * 4);
    const f32x4 qv = *(const f32x4*)(&q[j * 4]);
    d += qv[0] * kv[0] + qv[1] * kv[1] + qv[2] * kv[2] + qv[3] * kv[3];
  }
  d *= SCALE;

  float pm = d;
#pragma unroll
  for (int off = 32; off > 0; off >>= 1) pm = fmaxf(pm, __shfl_down(pm, off));
  if ((tid & 63) == 0) red[wv] = pm;
  __syncthreads();
  const float M = fmaxf(fmaxf(red[0], red[1]), fmaxf(red[2], red[3]));
  __syncthreads();
  const float p = __expf(d - M);
  sp[tid] = p;
  float ps = p;
#pragma unroll
  for (int off = 32; off > 0; off >>= 1) ps += __shfl_down(ps, off);
  if ((tid & 63) == 0) red[wv] = ps;
  __syncthreads();
  const float L = red[0] + red[1] + red[2] + red[3];

  if (tid < 192) {
    const int grp = tid >= HD;
    const int dd = tid - grp * HD;
    float acc = 0.f;
    const float* vp = vg + (size_t)(g * 256 + grp * 128) * KVDIM + kh * HD + dd;
#pragma unroll 4
    for (int i = 0; i < 128; ++i)
      acc = fmaf(sp[grp * 128 + i], vp[(size_t)i * KVDIM], acc);
    od[grp][dd] = acc;
  }
  __syncthreads();
  if (tid < HD) gO[((size_t)h * NGB + g) * HD + tid] = od[0][tid] + od[1][tid];
  if (tid == 0) { gM[h * NGB + g] = M; gL[h * NGB + g] = L; }
}

__global__ void global_attn_comb(const float* __restrict__ gM,
                                 const float* __restrict__ gL,
                                 const float* __restrict__ gO,
                                 ushort* __restrict__ obf) {
  const int h = blockIdx.x;
  const int d = threadIdx.x;
  if (d >= HD) return;
  float M = -1e30f;
  for (int g = 0; g < NGB; ++g) M = fmaxf(M, gM[h * NGB + g]);
  float L = 0.f, O = 0.f;
  for (int g = 0; g < NGB; ++g) {
    const float e = __expf(gM[h * NGB + g] - M);
    L += gL[h * NGB + g] * e;
    O += gO[((size_t)h * NGB + g) * HD + d] * e;
  }
  obf[h * HD + d] = f2bf(O / L);
}

// ---------------------------------------------------------------------------
// Launch
// ---------------------------------------------------------------------------
extern "C" void kernel_launch(void* const* d_in, const int* in_sizes, int n_in,
                              void* d_out, int out_size, void* d_ws, size_t ws_size,
                              hipStream_t stream) {
  const float* x     = (const float*)d_in[0];
  const float* cosf  = (const float*)d_in[1];
  const float* sinf  = (const float*)d_in[2];
  const int*   pid   = (const int*)d_in[3];
  const float* W_qs  = (const float*)d_in[4];
  const float* W_ks  = (const float*)d_in[5];
  const float* W_vs  = (const float*)d_in[6];
  const float* W_qg  = (const float*)d_in[7];
  const float* W_kg  = (const float*)d_in[8];
  const float* W_vg  = (const float*)d_in[9];
  const float* W_o   = (const float*)d_in[10];
  float* out = (float*)d_out;

  char* p = (char*)d_ws;
  auto alloc = [&](size_t bytes) { char* r = p; p += (bytes + 255) & ~(size_t)255; return r; };
  float*  kg     = (float*)alloc((size_t)T_LEN * KVDIM * 4);
  float*  vg     = (float*)alloc((size_t)T_LEN * KVDIM * 4);
  float*  qg0    = (float*)alloc(DMODEL * 4);
  ushort* x_bf   = (ushort*)alloc((size_t)T_LEN * DMODEL * 2);
  ushort* q_bf   = (ushort*)alloc((size_t)T_LEN * DMODEL * 2);
  ushort* attnbf = (ushort*)alloc((size_t)T_LEN * DMODEL * 2);
  ushort* k_bf   = (ushort*)alloc((size_t)T_LEN * KVDIM * 2);
  ushort* v_bf   = (ushort*)alloc((size_t)T_LEN * KVDIM * 2);
  ushort* vt_g   = (ushort*)alloc((size_t)KVDIM * T_LEN * 2);
  ushort* Wall   = (ushort*)alloc((size_t)NPROJ * DMODEL * 2);  // q + 4 KV
  ushort* Wo_t   = (ushort*)alloc((size_t)DMODEL * DMODEL * 2);
  float*  gM     = (float*)alloc((size_t)NH * NGB * 4);
  float*  gL     = (float*)alloc((size_t)NH * NGB * 4);
  float*  gO     = (float*)alloc((size_t)NH * NGB * HD * 4);

  const dim3 blk(256);
  const int nX4 = (T_LEN * DMODEL) / 4;

  // bf16 conversions / weight transposes (packed into Wall)
  convert_bf16<<<(nX4 + 255) / 256, blk, 0, stream>>>(x, x_bf, nX4);
  transpose_bf16<<<dim3(DMODEL / 32, DMODEL / 32), blk, 0, stream>>>(W_qs, Wall, DMODEL, DMODEL);
  transpose_bf16<<<dim3(DMODEL / 32, DMODEL / 32), blk, 0, stream>>>(W_o,  Wo_t, DMODEL, DMODEL);
  transpose_bf16_kv4<<<dim3(KVDIM / 32, DMODEL / 32, 4), blk, 0, stream>>>(
      W_ks, W_vs, W_kg, W_vg, Wall + (size_t)DMODEL * DMODEL);

  // Unified projection GEMM (256^2 deep-pipelined) with fused RoPE epilogue
  gemm_proj256<<<dim3(NPROJ / 256, T_LEN / 256), dim3(512), 0, stream>>>(
      x_bf, Wall, q_bf, k_bf, v_bf, kg, vg, cosf, sinf, pid);

  // qg row 0 (RoPE at pos 0 is identity -> skipped)
  qg0_zero<<<DMODEL / 256, blk, 0, stream>>>(qg0);
  qg0_split<<<dim3(DMODEL / 256, DMODEL / 128), blk, 0, stream>>>(x, W_qg, qg0);

  // V pre-transpose for local attention
  transpose_u16<<<dim3(KVDIM / 32, T_LEN / 32), blk, 0, stream>>>(v_bf, vt_g);

  // Attention
  local_attn_v4<<<dim3(T_LEN / 64, NH), blk, 0, stream>>>(
      q_bf, k_bf, vt_g, kg, vg, attnbf);
  global_attn_part<<<dim3(NH, NGB), blk, 0, stream>>>(qg0, kg, vg, gM, gL, gO);
  global_attn_comb<<<NH, dim3(128), 0, stream>>>(gM, gL, gO, attnbf);

  // Output projection (256^2 deep-pipelined)
  gemm_out256<<<dim3(DMODEL / 256, T_LEN / 256), dim3(512), 0, stream>>>(
      attnbf, Wo_t, out);
}

// Round 4
// 500.474 us; speedup vs baseline: 1.0071x; 1.0071x over previous
//
#include <hip/hip_runtime.h>

// Problem constants
#define T_LEN 8192
#define DMODEL 1536
#define NH 16
#define NKV 4
#define HD 96
#define KVDIM (NKV * HD)   // 384
#define W2 256             // WINDOW/2
#define NFREQ 48           // HD/2
#define NGB 32             // global-attention split-k blocks per head
#define NPROJ 3072         // total projection output columns (q + k + v + kg + vg)

static constexpr float SCALE = 0.10206207261596577f; // 1/sqrt(96)

typedef float f32x4 __attribute__((ext_vector_type(4)));
typedef short short8 __attribute__((ext_vector_type(8)));
typedef unsigned short ushort;

__device__ __forceinline__ ushort f2bf(float f) {
  unsigned int x = __float_as_uint(f);
  return (ushort)((x + 0x7FFFu + ((x >> 16) & 1u)) >> 16);
}
__device__ __forceinline__ float bf2f(ushort u) {
  return __uint_as_float((unsigned int)u << 16);
}
__device__ __forceinline__ void load_lds16(const void* g, void* l) {
  __builtin_amdgcn_global_load_lds(
      (const __attribute__((address_space(1))) void*)g,
      (__attribute__((address_space(3))) void*)l, 16, 0, 0);
}

// ---------------------------------------------------------------------------
// Elementwise fp32 -> bf16
// ---------------------------------------------------------------------------
__global__ __launch_bounds__(256) void convert_bf16(
    const float* __restrict__ in, ushort* __restrict__ out, int n4) {
  const int i = blockIdx.x * 256 + threadIdx.x;
  if (i >= n4) return;
  const f32x4 v = *(const f32x4*)&in[i * 4];
  ushort o[4] = {f2bf(v[0]), f2bf(v[1]), f2bf(v[2]), f2bf(v[3])};
  *(unsigned long long*)&out[i * 4] =
      (unsigned long long)o[0] | ((unsigned long long)o[1] << 16) |
      ((unsigned long long)o[2] << 32) | ((unsigned long long)o[3] << 48);
}

// ---------------------------------------------------------------------------
// W[K][N] fp32 -> Wt[N][K] bf16 (single)
// ---------------------------------------------------------------------------
__global__ __launch_bounds__(256) void transpose_bf16(
    const float* __restrict__ W, ushort* __restrict__ Wt, int K, int N) {
  __shared__ ushort tile[32][33];
  const int tx = threadIdx.x & 31;
  const int ty = threadIdx.x >> 5;
  const int n0 = blockIdx.x * 32;
  const int k0 = blockIdx.y * 32;
#pragma unroll
  for (int i = 0; i < 32; i += 8)
    tile[tx][ty + i] = f2bf(W[(size_t)(k0 + ty + i) * N + n0 + tx]);
  __syncthreads();
#pragma unroll
  for (int i = 0; i < 32; i += 8)
    Wt[(size_t)(n0 + ty + i) * K + k0 + tx] = tile[ty + i][tx];
}

// Batched version for the 4 KV weights (z selects source).
__global__ __launch_bounds__(256) void transpose_bf16_kv4(
    const float* __restrict__ Wk, const float* __restrict__ Wv,
    const float* __restrict__ Wkg, const float* __restrict__ Wvg,
    ushort* __restrict__ Wt) {
  const int z = blockIdx.z;
  const float* W = (z == 0) ? Wk : (z == 1) ? Wv : (z == 2) ? Wkg : Wvg;
  ushort* dst = Wt + (size_t)z * KVDIM * DMODEL;
  __shared__ ushort tile[32][33];
  const int tx = threadIdx.x & 31;
  const int ty = threadIdx.x >> 5;
  const int n0 = blockIdx.x * 32;
  const int k0 = blockIdx.y * 32;
#pragma unroll
  for (int i = 0; i < 32; i += 8)
    tile[tx][ty + i] = f2bf(W[(size_t)(k0 + ty + i) * KVDIM + n0 + tx]);
  __syncthreads();
#pragma unroll
  for (int i = 0; i < 32; i += 8)
    dst[(size_t)(n0 + ty + i) * DMODEL + k0 + tx] = tile[ty + i][tx];
}

// ---------------------------------------------------------------------------
// bf16 [T][KVDIM] -> bf16 [KVDIM][T] (V pre-transpose for local attn)
// ---------------------------------------------------------------------------
__global__ __launch_bounds__(256) void transpose_u16(
    const ushort* __restrict__ in, ushort* __restrict__ out) {
  __shared__ ushort tile[32][33];
  const int tx = threadIdx.x & 31;
  const int ty = threadIdx.x >> 5;
  const int c0 = blockIdx.x * 32;   // dim
  const int r0 = blockIdx.y * 32;   // t
#pragma unroll
  for (int i = 0; i < 32; i += 8)
    tile[ty + i][tx] = in[(size_t)(r0 + ty + i) * KVDIM + c0 + tx];
  __syncthreads();
#pragma unroll
  for (int i = 0; i < 32; i += 8)
    out[(size_t)(c0 + ty + i) * T_LEN + r0 + tx] = tile[tx][ty + i];
}

// ---------------------------------------------------------------------------
// 256x256 8-phase bf16 GEMM core (m201 schedule port), staging FIXED for the
// global_load_lds hardware rule: LDS dest is WAVE-UNIFORM base + lane*16.
//
// K = 1536 = 24 K-tiles of BK=64. 8 waves (2M x 4N), per-wave output 128x64.
// LDS: 2 buffers x 64KB; buffer = A[2 slices][256 rows][32 k] (16KB/slice at
// s*16384) + B[2][256][32] (at 32768 + s*16384). Chunk g = row*4 + kc (16B)
// lives at byte g*16 within its slice region (row*64 + kc*16 -- m97 geometry,
// ~conflict-free for the quad*16 fragment reads).
//
// Staging: slice = 32 segments x 1KB. Waves 0-3 stage A segs w*4+i, waves
// 4-7 stage B segs (w-4)*4+i, i=0..3. Each load_lds16: uniform dest
// slicebase + seg*1024; per-lane source row = seg*16 + (lane>>2),
// kc = lane&3 -> lane l's 16B lands at seg*1024 + l*16 = chunk g = seg*64+l.
// 4 loads/slice/wave (same vmcnt arithmetic as the verified ladder).
//
// Per K-tile: 4 phases (k-slice s x nf-half h), 16 MFMA each:
//   phi0 (s0,h0): 8 A-reads + 2 B-reads; stage slice0 of tile t+1
//   phi1 (s0,h1): 2 B-reads;             stage slice1 of t+1; WAITV(8)
//   phi2 (s1,h0): 8 A-reads + 2 B-reads
//   phi3 (s1,h1): 2 B-reads;                                  WAITV(4)
// Each phase: reads -> stage -> [wait] -> s_barrier -> lgkmcnt(0) ->
// sched_barrier(0) -> setprio(1) 16 MFMA setprio(0) -> s_barrier.
//
// Wait derivation (4 loads/slice/wave, FIFO): WAITV(8) at phi1 confirms
// t:s1 (first read phi2); WAITV(4) at phi3 confirms t+1:s0 (first read
// next phi0). Steady state never drains to 0 (T4); peeled tile 23 drains.
// ---------------------------------------------------------------------------
#define WAITV(N) asm volatile("s_waitcnt vmcnt(" #N ")" ::: "memory")
#define LGKM0()  asm volatile("s_waitcnt lgkmcnt(0)" ::: "memory")
#define SBAR()   __builtin_amdgcn_s_barrier()
#define SCHEDB() __builtin_amdgcn_sched_barrier(0)

#define STAGE_SLICE(tt, s)                                                    \
  { char* db_ = lds + (((tt) & 1) << 16) + (s) * 16384 + dbase;               \
    const ushort* sp_ = srcBase + (tt) * 64 + (s) * 32;                       \
    load_lds16(sp_, db_);                                                     \
    load_lds16(sp_ + 16 * 1536, db_ + 1024);                                  \
    load_lds16(sp_ + 32 * 1536, db_ + 2048);                                  \
    load_lds16(sp_ + 48 * 1536, db_ + 3072); }

#define PH_A(bufT, s)                                                         \
  _Pragma("unroll") for (int mf = 0; mf < 8; ++mf)                            \
      af[mf] = *(const short8*)((bufT) + (s) * 16384 + aoff + mf * 1024);

#define PH_B2(bufT, s, h)                                                     \
  bq0 = *(const short8*)((bufT) + (s) * 16384 + boff + ((h) * 2) * 1024);     \
  bq1 = *(const short8*)((bufT) + (s) * 16384 + boff + ((h) * 2 + 1) * 1024);

#define PH_MFMA(h)                                                            \
  __builtin_amdgcn_s_setprio(1);                                              \
  _Pragma("unroll") for (int mf = 0; mf < 8; ++mf) {                          \
    acc[mf][(h) * 2] = __builtin_amdgcn_mfma_f32_16x16x32_bf16(               \
        af[mf], bq0, acc[mf][(h) * 2], 0, 0, 0);                              \
    acc[mf][(h) * 2 + 1] = __builtin_amdgcn_mfma_f32_16x16x32_bf16(           \
        af[mf], bq1, acc[mf][(h) * 2 + 1], 0, 0, 0);                          \
  }                                                                           \
  __builtin_amdgcn_s_setprio(0);

#define GEMM8P_PRE(APTR, BPTR, GXDIM)                                         \
  __shared__ __align__(16) char lds[131072];                                  \
  const int tid = threadIdx.x;                                                \
  const int lane = tid & 63;                                                  \
  const int lo = lane & 15;                                                   \
  const int quad = lane >> 4;                                                 \
  const int wm = (tid >> 6) >> 2;                                             \
  const int wn = (tid >> 6) & 3;                                              \
  /* T1: bijective XCD swizzle (nwg % 8 == 0 for both call sites) */          \
  const int lid_ = (int)blockIdx.y * (GXDIM) + (int)blockIdx.x;               \
  const int per_ = ((GXDIM) * (int)gridDim.y) >> 3;                           \
  const int nl_ = (lid_ & 7) * per_ + (lid_ >> 3);                            \
  const int bx_ = nl_ % (GXDIM);                                              \
  const int by_ = nl_ / (GXDIM);                                              \
  const int m0 = by_ * 256;                                                   \
  const int n0 = bx_ * 256;                                                   \
  /* staging assignment: waves 0-3 -> A, waves 4-7 -> B */                    \
  const int wv_ = tid >> 6;                                                   \
  const bool isB_ = wv_ >= 4;                                                 \
  const int wq_ = isB_ ? wv_ - 4 : wv_;                                       \
  const ushort* srcBase = (isB_ ? (BPTR) + (size_t)n0 * 1536                  \
                                : (APTR) + (size_t)m0 * 1536) +               \
                          (size_t)(wq_ * 64 + (lane >> 2)) * 1536 +           \
                          (lane & 3) * 8;                                     \
  const int dbase = (isB_ ? 32768 : 0) + wq_ * 4096;                          \
  /* fragment read offsets: 64-B rows, quad selects 16B chunk */              \
  const int aoff = (wm * 128 + lo) * 64 + quad * 16;                          \
  const int boff = 32768 + (wn * 64 + lo) * 64 + quad * 16;                   \
  f32x4 acc[8][4];                                                            \
  _Pragma("unroll") for (int i = 0; i < 8; ++i)                               \
      _Pragma("unroll") for (int j = 0; j < 4; ++j)                           \
          acc[i][j] = {0.f, 0.f, 0.f, 0.f};

#define GEMM8P_LOOP()                                                         \
  short8 af[8], bq0, bq1;                                                     \
  STAGE_SLICE(0, 0) STAGE_SLICE(0, 1)                                         \
  WAITV(4);                                                                   \
  SBAR();                                                                     \
  _Pragma("unroll 1") for (int t = 0; t < 23; ++t) {                          \
    const char* bufT = lds + ((t & 1) << 16);                                 \
    PH_A(bufT, 0) PH_B2(bufT, 0, 0)                                           \
    STAGE_SLICE(t + 1, 0)                                                     \
    SBAR(); LGKM0(); SCHEDB(); PH_MFMA(0) SBAR();                             \
    PH_B2(bufT, 0, 1)                                                         \
    STAGE_SLICE(t + 1, 1)                                                     \
    WAITV(8);                                                                 \
    SBAR(); LGKM0(); SCHEDB(); PH_MFMA(1) SBAR();                             \
    PH_A(bufT, 1) PH_B2(bufT, 1, 0)                                           \
    SBAR(); LGKM0(); SCHEDB(); PH_MFMA(0) SBAR();                             \
    PH_B2(bufT, 1, 1)                                                         \
    WAITV(4);                                                                 \
    SBAR(); LGKM0(); SCHEDB(); PH_MFMA(1) SBAR();                             \
  }                                                                           \
  { const char* bufT = lds + 65536; /* tile 23 */                             \
    PH_A(bufT, 0) PH_B2(bufT, 0, 0)                                           \
    SBAR(); LGKM0(); SCHEDB(); PH_MFMA(0) SBAR();                             \
    PH_B2(bufT, 0, 1)                                                         \
    WAITV(0);                                                                 \
    SBAR(); LGKM0(); SCHEDB(); PH_MFMA(1) SBAR();                             \
    PH_A(bufT, 1) PH_B2(bufT, 1, 0)                                           \
    SBAR(); LGKM0(); SCHEDB(); PH_MFMA(0) SBAR();                             \
    PH_B2(bufT, 1, 1)                                                         \
    SBAR(); LGKM0(); SCHEDB(); PH_MFMA(1) SBAR();                             \
  }

// ---------------------------------------------------------------------------
// Unified projection GEMM: A[8192][1536] @ Wall[3072][1536]^T, 256^2 tiles.
// Column sections: [0,1536) q (rope, bf16) | [1536,1920) k (rope, bf16) |
// [1920,2304) v (bf16) | [2304,2688) kg (rope, f32) | [2688,3072) vg (f32).
// Sections are resolved PER COLUMN (256-wide blocks straddle boundaries).
// ---------------------------------------------------------------------------
__global__ __launch_bounds__(512) void gemm_proj256(
    const ushort* __restrict__ A, const ushort* __restrict__ Wall,
    ushort* __restrict__ q_bf, ushort* __restrict__ k_bf,
    ushort* __restrict__ v_bf, float* __restrict__ kg,
    float* __restrict__ vg, const float* __restrict__ cosf,
    const float* __restrict__ sinf, const int* __restrict__ pid) {
  GEMM8P_PRE(A, Wall, 12)
  GEMM8P_LOOP()

  // ---- epilogue: fused RoPE + dtype routing ----
  __syncthreads();  // all LDS reads of the K-loop done; reuse lds
  const int xb = bx_;
  const bool blkRope = (xb <= 7) || (xb == 9) || (xb == 10);
  int* PidS = (int*)lds;                       // [256]
  unsigned int* CoefS = (unsigned int*)(lds + 1024);  // [256][48] cos|sin bf16
  if (blkRope) {
    if (tid < 256) PidS[tid] = pid[m0 + tid];
    __syncthreads();
#pragma unroll
    for (int j = 0; j < 24; ++j) {
      const int idx = j * 512 + tid;          // 0..12287
      const int rr = idx / 48;
      const int ff = idx - rr * 48;
      const int pos = PidS[rr];
      CoefS[idx] = (unsigned int)f2bf(cosf[(size_t)pos * NFREQ + ff]) |
                   ((unsigned int)f2bf(sinf[(size_t)pos * NFREQ + ff]) << 16);
    }
    __syncthreads();
  }

#pragma unroll
  for (int nf = 0; nf < 4; ++nf) {
    const int cc = n0 + wn * 64 + nf * 16 + lo;
    int sec, cbase;
    if (cc < 1536)      { sec = 0; cbase = 0; }
    else if (cc < 1920) { sec = 1; cbase = 1536; }
    else if (cc < 2304) { sec = 2; cbase = 1920; }
    else if (cc < 2688) { sec = 3; cbase = 2304; }
    else                { sec = 4; cbase = 2688; }
    const int col = cc - cbase;
    const int d = col % HD;
    const int fi = d >> 1;
    const bool doRope = (sec == 0) || (sec == 1) || (sec == 3);
#pragma unroll
    for (int mf = 0; mf < 8; ++mf) {
      const int lr0 = wm * 128 + mf * 16 + quad * 4;
#pragma unroll
      for (int r = 0; r < 4; ++r) {
        const int lr = lr0 + r;
        float v = acc[mf][nf][r];
        const float pe = __shfl_xor(v, 1);   // partner column (col^1)
        if (doRope) {
          const unsigned int pk = CoefS[lr * 48 + fi];
          const float co = bf2f((ushort)(pk & 0xFFFF));
          const float si = bf2f((ushort)(pk >> 16));
          v = (d & 1) ? fmaf(pe, si, v * co) : fmaf(v, co, -pe * si);
        }
        const int trow = m0 + lr;
        if (sec == 0)      q_bf[(size_t)trow * DMODEL + col] = f2bf(v);
        else if (sec == 1) k_bf[(size_t)trow * KVDIM + col] = f2bf(v);
        else if (sec == 2) v_bf[(size_t)trow * KVDIM + col] = f2bf(v);
        else if (sec == 3) kg[(size_t)trow * KVDIM + col] = v;
        else               vg[(size_t)trow * KVDIM + col] = v;
      }
    }
  }
}

// ---------------------------------------------------------------------------
// Output projection GEMM: attn[8192][1536] @ Wo_t[1536][1536]^T -> f32
// ---------------------------------------------------------------------------
__global__ __launch_bounds__(512) void gemm_out256(
    const ushort* __restrict__ A, const ushort* __restrict__ Bt,
    float* __restrict__ C) {
  GEMM8P_PRE(A, Bt, 6)
  GEMM8P_LOOP()
#pragma unroll
  for (int mf = 0; mf < 8; ++mf) {
    const int r0 = m0 + wm * 128 + mf * 16 + quad * 4;
#pragma unroll
    for (int nf = 0; nf < 4; ++nf) {
      const int cc = n0 + wn * 64 + nf * 16 + lo;
#pragma unroll
      for (int r = 0; r < 4; ++r)
        C[(size_t)(r0 + r) * DMODEL + cc] = acc[mf][nf][r];
    }
  }
}

// ---------------------------------------------------------------------------
// qg row 0: zero + split-k atomics
// ---------------------------------------------------------------------------
__global__ void qg0_zero(float* __restrict__ qg0) {
  qg0[blockIdx.x * 256 + threadIdx.x] = 0.f;
}
__global__ __launch_bounds__(256) void qg0_split(
    const float* __restrict__ x, const float* __restrict__ W,
    float* __restrict__ qg0) {
  const int j = blockIdx.x * 256 + threadIdx.x;
  const int k0 = blockIdx.y * 128;
  float acc = 0.f;
#pragma unroll 8
  for (int k = k0; k < k0 + 128; ++k)
    acc = fmaf(x[k], W[(size_t)k * DMODEL + j], acc);
  atomicAdd(&qg0[j], acc);
}

// ---------------------------------------------------------------------------
// Local attention v4: MFMA bf16 flash tiles; V staged from pre-transposed
// Vt_g[KVDIM][T] via global_load_lds.
// ---------------------------------------------------------------------------
__global__ __launch_bounds__(256) void local_attn_v4(
    const ushort* __restrict__ qbf, const ushort* __restrict__ kbf,
    const ushort* __restrict__ vtg, const float* __restrict__ kg,
    const float* __restrict__ vg, ushort* __restrict__ obf) {
  __shared__ ushort Qb[3 * 64 * 32];
  __shared__ ushort Kb[3 * 64 * 32];
  __shared__ ushort Vt[2 * 96 * 32];   // panel kp: [96 dims][32 keys]
  __shared__ ushort Pb[4][2 * 16 * 32];
  __shared__ float Kg0[HD];
  __shared__ float Vg0[HD];

  const int t0 = blockIdx.x * 64;
  const int h  = blockIdx.y;
  const int kh = h >> 2;
  const int tid = threadIdx.x;
  const int w    = tid >> 6;
  const int lane = tid & 63;
  const int lo   = lane & 15;
  const int quad = lane >> 4;

  {
    const int rem = w * 64 + lane;
    const int row = rem >> 2;
    const int sub = (rem & 3) * 8;
#pragma unroll
    for (int j = 0; j < 3; ++j) {
      load_lds16(qbf + (size_t)(t0 + row) * DMODEL + h * HD + j * 32 + sub,
                 (char*)Qb + (j * 256 + w * 64) * 16);
    }
  }
  if (tid < HD) {
    Kg0[tid] = kg[kh * HD + tid];   // row 0 (rope at pos 0 = identity)
    Vg0[tid] = vg[kh * HD + tid];
  }

  f32x4 O[6];
#pragma unroll
  for (int i = 0; i < 6; ++i) O[i] = {0.f, 0.f, 0.f, 0.f};
  float m_run[4], l_run[4];
#pragma unroll
  for (int r = 0; r < 4; ++r) { m_run[r] = -1e30f; l_run[r] = 0.f; }

  __syncthreads();

  for (int ti = 0; ti < 5; ++ti) {
    const int kb = t0 - W2 + ti * 64;
    if (kb < 0) continue;

    {
      const int rem = w * 64 + lane;
      const int row = rem >> 2;
      const int sub = (rem & 3) * 8;
#pragma unroll
      for (int j = 0; j < 3; ++j) {
        load_lds16(kbf + (size_t)(kb + row) * KVDIM + kh * HD + j * 32 + sub,
                   (char*)Kb + (j * 256 + w * 64) * 16);
      }
#pragma unroll
      for (int j = 0; j < 3; ++j) {
        const int cc = j * 256 + w * 64 + lane;
        const int half = cc / 384;
        const int rm2 = cc - half * 384;
        const int dd = rm2 >> 2;
        const int sb = (rm2 & 3) * 8;
        load_lds16(vtg + (size_t)(kh * HD + dd) * T_LEN + kb + half * 32 + sb,
                   (char*)Vt + (j * 256 + w * 64) * 16);
      }
    }
    __syncthreads();

    short8 af[3];
#pragma unroll
    for (int p = 0; p < 3; ++p)
      af[p] = *(const short8*)&Qb[p * 2048 + (w * 16 + lo) * 32 + quad * 8];
    f32x4 s4[4];
#pragma unroll
    for (int nt = 0; nt < 4; ++nt) s4[nt] = {0.f, 0.f, 0.f, 0.f};
#pragma unroll
    for (int nt = 0; nt < 4; ++nt)
#pragma unroll
      for (int p = 0; p < 3; ++p) {
        const short8 bf8 =
            *(const short8*)&Kb[p * 2048 + (nt * 16 + lo) * 32 + quad * 8];
        s4[nt] = __builtin_amdgcn_mfma_f32_16x16x32_bf16(af[p], bf8, s4[nt], 0, 0, 0);
      }

    float alpha[4];
#pragma unroll
    for (int r = 0; r < 4; ++r) {
      const int tq = t0 + w * 16 + quad * 4 + r;
      float sv[4], rm = -1e30f;
#pragma unroll
      for (int nt = 0; nt < 4; ++nt) {
        const int p = kb + nt * 16 + lo;
        const bool ok = (p >= 1) && (p <= tq) && (p + W2 >= tq);
        sv[nt] = ok ? s4[nt][r] * SCALE : -1e30f;
        rm = fmaxf(rm, sv[nt]);
      }
#pragma unroll
      for (int mo = 1; mo < 16; mo <<= 1) rm = fmaxf(rm, __shfl_xor(rm, mo));
      const float m_new = fmaxf(m_run[r], rm);
      float psum = 0.f;
#pragma unroll
      for (int nt = 0; nt < 4; ++nt) {
        const float pv = (sv[nt] > -1e29f) ? __expf(sv[nt] - m_new) : 0.f;
        Pb[w][(nt >> 1) * 512 + (quad * 4 + r) * 32 + (nt & 1) * 16 + lo] = f2bf(pv);
        psum += pv;
      }
#pragma unroll
      for (int mo = 1; mo < 16; mo <<= 1) psum += __shfl_xor(psum, mo);
      alpha[r] = __expf(m_run[r] - m_new);
      l_run[r] = l_run[r] * alpha[r] + psum;
      m_run[r] = m_new;
    }

#pragma unroll
    for (int nt6 = 0; nt6 < 6; ++nt6)
#pragma unroll
      for (int r = 0; r < 4; ++r) O[nt6][r] *= alpha[r];

    short8 pa[2];
#pragma unroll
    for (int kp = 0; kp < 2; ++kp)
      pa[kp] = *(const short8*)&Pb[w][kp * 512 + lo * 32 + quad * 8];
#pragma unroll
    for (int nt6 = 0; nt6 < 6; ++nt6)
#pragma unroll
      for (int kp = 0; kp < 2; ++kp) {
        const short8 vb8 =
            *(const short8*)&Vt[kp * 3072 + (nt6 * 16 + lo) * 32 + quad * 8];
        O[nt6] = __builtin_amdgcn_mfma_f32_16x16x32_bf16(pa[kp], vb8, O[nt6], 0, 0, 0);
      }
    __syncthreads();
  }

  float sg[4];
#pragma unroll
  for (int r = 0; r < 4; ++r) {
    const int row = w * 16 + quad * 4 + r;
    float part = 0.f;
#pragma unroll
    for (int i = 0; i < 6; ++i) {
      const int d = lo * 6 + i;
      part += bf2f(Qb[(d >> 5) * 2048 + row * 32 + (d & 31)]) * Kg0[d];
    }
#pragma unroll
    for (int mo = 1; mo < 16; mo <<= 1) part += __shfl_xor(part, mo);
    sg[r] = part * SCALE;
  }
#pragma unroll
  for (int r = 0; r < 4; ++r) {
    const float m_new = fmaxf(m_run[r], sg[r]);
    const float al = __expf(m_run[r] - m_new);
    const float pg = __expf(sg[r] - m_new);
    const float inv = 1.0f / (l_run[r] * al + pg);
    ushort* dst = obf + (size_t)(t0 + w * 16 + quad * 4 + r) * DMODEL + h * HD;
#pragma unroll
    for (int nt6 = 0; nt6 < 6; ++nt6) {
      const int d = nt6 * 16 + lo;
      dst[d] = f2bf((O[nt6][r] * al + pg * Vg0[d]) * inv);
    }
  }
}

// ---------------------------------------------------------------------------
// Global row, split-k partials: grid (NH, NGB); 256 keys per block.
// ---------------------------------------------------------------------------
__global__ __launch_bounds__(256) void global_attn_part(
    const float* __restrict__ qg0, const float* __restrict__ kg,
    const float* __restrict__ vg, float* __restrict__ gM,
    float* __restrict__ gL, float* __restrict__ gO) {
  const int h = blockIdx.x;
  const int g = blockIdx.y;
  const int kh = h >> 2;
  const int tid = threadIdx.x;
  const int wv = tid >> 6;
  __shared__ float q[HD];
  __shared__ float sp[256];
  __shared__ float red[4];
  __shared__ float od[2][HD];

  if (tid < HD) q[tid] = qg0[h * HD + tid];
  __syncthreads();

  const int key = g * 256 + tid;
  const float* kp = kg + (size_t)key * KVDIM + kh * HD;
  float d = 0.f;
#pragma unroll
  for (int j = 0; j < 24; ++j) {
    const f32x4 kv = *(const f32x4*)(kp + j * 4);
    const f32x4 qv = *(const f32x4*)(&q[j * 4]);
    d += qv[0] * kv[0] + qv[1] * kv[1] + qv[2] * kv[2] + qv[3] * kv[3];
  }
  d *= SCALE;

  float pm = d;
#pragma unroll
  for (int off = 32; off > 0; off >>= 1) pm = fmaxf(pm, __shfl_down(pm, off));
  if ((tid & 63) == 0) red[wv] = pm;
  __syncthreads();
  const float M = fmaxf(fmaxf(red[0], red[1]), fmaxf(red[2], red[3]));
  __syncthreads();
  const float p = __expf(d - M);
  sp[tid] = p;
  float ps = p;
#pragma unroll
  for (int off = 32; off > 0; off >>= 1) ps += __shfl_down(ps, off);
  if ((tid & 63) == 0) red[wv] = ps;
  __syncthreads();
  const float L = red[0] + red[1] + red[2] + red[3];

  if (tid < 192) {
    const int grp = tid >= HD;
    const int dd = tid - grp * HD;
    float acc = 0.f;
    const float* vp = vg + (size_t)(g * 256 + grp * 128) * KVDIM + kh * HD + dd;
#pragma unroll 4
    for (int i = 0; i < 128; ++i)
      acc = fmaf(sp[grp * 128 + i], vp[(size_t)i * KVDIM], acc);
    od[grp][dd] = acc;
  }
  __syncthreads();
  if (tid < HD) gO[((size_t)h * NGB + g) * HD + tid] = od[0][tid] + od[1][tid];
  if (tid == 0) { gM[h * NGB + g] = M; gL[h * NGB + g] = L; }
}

__global__ void global_attn_comb(const float* __restrict__ gM,
                                 const float* __restrict__ gL,
                                 const float* __restrict__ gO,
                                 ushort* __restrict__ obf) {
  const int h = blockIdx.x;
  const int d = threadIdx.x;
  if (d >= HD) return;
  float M = -1e30f;
  for (int g = 0; g < NGB; ++g) M = fmaxf(M, gM[h * NGB + g]);
  float L = 0.f, O = 0.f;
  for (int g = 0; g < NGB; ++g) {
    const float e = __expf(gM[h * NGB + g] - M);
    L += gL[h * NGB + g] * e;
    O += gO[((size_t)h * NGB + g) * HD + d] * e;
  }
  obf[h * HD + d] = f2bf(O / L);
}

// ---------------------------------------------------------------------------
// Launch
// ---------------------------------------------------------------------------
extern "C" void kernel_launch(void* const* d_in, const int* in_sizes, int n_in,
                              void* d_out, int out_size, void* d_ws, size_t ws_size,
                              hipStream_t stream) {
  const float* x     = (const float*)d_in[0];
  const float* cosf  = (const float*)d_in[1];
  const float* sinf  = (const float*)d_in[2];
  const int*   pid   = (const int*)d_in[3];
  const float* W_qs  = (const float*)d_in[4];
  const float* W_ks  = (const float*)d_in[5];
  const float* W_vs  = (const float*)d_in[6];
  const float* W_qg  = (const float*)d_in[7];
  const float* W_kg  = (const float*)d_in[8];
  const float* W_vg  = (const float*)d_in[9];
  const float* W_o   = (const float*)d_in[10];
  float* out = (float*)d_out;

  char* p = (char*)d_ws;
  auto alloc = [&](size_t bytes) { char* r = p; p += (bytes + 255) & ~(size_t)255; return r; };
  float*  kg     = (float*)alloc((size_t)T_LEN * KVDIM * 4);
  float*  vg     = (float*)alloc((size_t)T_LEN * KVDIM * 4);
  float*  qg0    = (float*)alloc(DMODEL * 4);
  ushort* x_bf   = (ushort*)alloc((size_t)T_LEN * DMODEL * 2);
  ushort* q_bf   = (ushort*)alloc((size_t)T_LEN * DMODEL * 2);
  ushort* attnbf = (ushort*)alloc((size_t)T_LEN * DMODEL * 2);
  ushort* k_bf   = (ushort*)alloc((size_t)T_LEN * KVDIM * 2);
  ushort* v_bf   = (ushort*)alloc((size_t)T_LEN * KVDIM * 2);
  ushort* vt_g   = (ushort*)alloc((size_t)KVDIM * T_LEN * 2);
  ushort* Wall   = (ushort*)alloc((size_t)NPROJ * DMODEL * 2);  // q + 4 KV
  ushort* Wo_t   = (ushort*)alloc((size_t)DMODEL * DMODEL * 2);
  float*  gM     = (float*)alloc((size_t)NH * NGB * 4);
  float*  gL     = (float*)alloc((size_t)NH * NGB * 4);
  float*  gO     = (float*)alloc((size_t)NH * NGB * HD * 4);

  const dim3 blk(256);
  const int nX4 = (T_LEN * DMODEL) / 4;

  // bf16 conversions / weight transposes (packed into Wall)
  convert_bf16<<<(nX4 + 255) / 256, blk, 0, stream>>>(x, x_bf, nX4);
  transpose_bf16<<<dim3(DMODEL / 32, DMODEL / 32), blk, 0, stream>>>(W_qs, Wall, DMODEL, DMODEL);
  transpose_bf16<<<dim3(DMODEL / 32, DMODEL / 32), blk, 0, stream>>>(W_o,  Wo_t, DMODEL, DMODEL);
  transpose_bf16_kv4<<<dim3(KVDIM / 32, DMODEL / 32, 4), blk, 0, stream>>>(
      W_ks, W_vs, W_kg, W_vg, Wall + (size_t)DMODEL * DMODEL);

  // Unified projection GEMM (256^2 8-phase) with fused RoPE epilogue
  gemm_proj256<<<dim3(NPROJ / 256, T_LEN / 256), dim3(512), 0, stream>>>(
      x_bf, Wall, q_bf, k_bf, v_bf, kg, vg, cosf, sinf, pid);

  // qg row 0 (RoPE at pos 0 is identity -> skipped)
  qg0_zero<<<DMODEL / 256, blk, 0, stream>>>(qg0);
  qg0_split<<<dim3(DMODEL / 256, DMODEL / 128), blk, 0, stream>>>(x, W_qg, qg0);

  // V pre-transpose for local attention
  transpose_u16<<<dim3(KVDIM / 32, T_LEN / 32), blk, 0, stream>>>(v_bf, vt_g);

  // Attention
  local_attn_v4<<<dim3(T_LEN / 64, NH), blk, 0, stream>>>(
      q_bf, k_bf, vt_g, kg, vg, attnbf);
  global_attn_part<<<dim3(NH, NGB), blk, 0, stream>>>(qg0, kg, vg, gM, gL, gO);
  global_attn_comb<<<NH, dim3(128), 0, stream>>>(gM, gL, gO, attnbf);

  // Output projection (256^2 8-phase)
  gemm_out256<<<dim3(DMODEL / 256, T_LEN / 256), dim3(512), 0, stream>>>(
      attnbf, Wo_t, out);
}

// Round 5
// 462.672 us; speedup vs baseline: 1.0894x; 1.0817x over previous
//
#include <hip/hip_runtime.h>

// Problem constants
#define T_LEN 8192
#define DMODEL 1536
#define NH 16
#define NKV 4
#define HD 96
#define KVDIM (NKV * HD)   // 384
#define W2 256             // WINDOW/2
#define NFREQ 48           // HD/2
#define NGB 32             // global-attention split-k blocks per head
#define NPROJ 3072         // total projection output columns (q + k + v + kg + vg)

static constexpr float SCALE = 0.10206207261596577f; // 1/sqrt(96)

typedef float f32x4 __attribute__((ext_vector_type(4)));
typedef short short8 __attribute__((ext_vector_type(8)));
typedef unsigned short ushort;

__device__ __forceinline__ ushort f2bf(float f) {
  unsigned int x = __float_as_uint(f);
  return (ushort)((x + 0x7FFFu + ((x >> 16) & 1u)) >> 16);
}
__device__ __forceinline__ float bf2f(ushort u) {
  return __uint_as_float((unsigned int)u << 16);
}
__device__ __forceinline__ void load_lds16(const void* g, void* l) {
  __builtin_amdgcn_global_load_lds(
      (const __attribute__((address_space(1))) void*)g,
      (__attribute__((address_space(3))) void*)l, 16, 0, 0);
}

#define WAITV(N) asm volatile("s_waitcnt vmcnt(" #N ")" ::: "memory")
#define SBAR()   __builtin_amdgcn_s_barrier()

// ---------------------------------------------------------------------------
// Elementwise fp32 -> bf16
// ---------------------------------------------------------------------------
__global__ __launch_bounds__(256) void convert_bf16(
    const float* __restrict__ in, ushort* __restrict__ out, int n4) {
  const int i = blockIdx.x * 256 + threadIdx.x;
  if (i >= n4) return;
  const f32x4 v = *(const f32x4*)&in[i * 4];
  ushort o[4] = {f2bf(v[0]), f2bf(v[1]), f2bf(v[2]), f2bf(v[3])};
  *(unsigned long long*)&out[i * 4] =
      (unsigned long long)o[0] | ((unsigned long long)o[1] << 16) |
      ((unsigned long long)o[2] << 32) | ((unsigned long long)o[3] << 48);
}

// ---------------------------------------------------------------------------
// W[K][N] fp32 -> Wt[N][K] bf16 (single)
// ---------------------------------------------------------------------------
__global__ __launch_bounds__(256) void transpose_bf16(
    const float* __restrict__ W, ushort* __restrict__ Wt, int K, int N) {
  __shared__ ushort tile[32][33];
  const int tx = threadIdx.x & 31;
  const int ty = threadIdx.x >> 5;
  const int n0 = blockIdx.x * 32;
  const int k0 = blockIdx.y * 32;
#pragma unroll
  for (int i = 0; i < 32; i += 8)
    tile[tx][ty + i] = f2bf(W[(size_t)(k0 + ty + i) * N + n0 + tx]);
  __syncthreads();
#pragma unroll
  for (int i = 0; i < 32; i += 8)
    Wt[(size_t)(n0 + ty + i) * K + k0 + tx] = tile[ty + i][tx];
}

// Batched version for the 4 KV weights (z selects source).
__global__ __launch_bounds__(256) void transpose_bf16_kv4(
    const float* __restrict__ Wk, const float* __restrict__ Wv,
    const float* __restrict__ Wkg, const float* __restrict__ Wvg,
    ushort* __restrict__ Wt) {
  const int z = blockIdx.z;
  const float* W = (z == 0) ? Wk : (z == 1) ? Wv : (z == 2) ? Wkg : Wvg;
  ushort* dst = Wt + (size_t)z * KVDIM * DMODEL;
  __shared__ ushort tile[32][33];
  const int tx = threadIdx.x & 31;
  const int ty = threadIdx.x >> 5;
  const int n0 = blockIdx.x * 32;
  const int k0 = blockIdx.y * 32;
#pragma unroll
  for (int i = 0; i < 32; i += 8)
    tile[tx][ty + i] = f2bf(W[(size_t)(k0 + ty + i) * KVDIM + n0 + tx]);
  __syncthreads();
#pragma unroll
  for (int i = 0; i < 32; i += 8)
    dst[(size_t)(n0 + ty + i) * DMODEL + k0 + tx] = tile[ty + i][tx];
}

// ---------------------------------------------------------------------------
// bf16 [T][KVDIM] -> bf16 [KVDIM][T] (V pre-transpose for local attn)
// ---------------------------------------------------------------------------
__global__ __launch_bounds__(256) void transpose_u16(
    const ushort* __restrict__ in, ushort* __restrict__ out) {
  __shared__ ushort tile[32][33];
  const int tx = threadIdx.x & 31;
  const int ty = threadIdx.x >> 5;
  const int c0 = blockIdx.x * 32;   // dim
  const int r0 = blockIdx.y * 32;   // t
#pragma unroll
  for (int i = 0; i < 32; i += 8)
    tile[ty + i][tx] = in[(size_t)(r0 + ty + i) * KVDIM + c0 + tx];
  __syncthreads();
#pragma unroll
  for (int i = 0; i < 32; i += 8)
    out[(size_t)(c0 + ty + i) * T_LEN + r0 + tx] = tile[tx][ty + i];
}

// ---------------------------------------------------------------------------
// bf16 MFMA GEMM core (m97 structure) -- PROVEN R0 baseline. Caller must
// declare LDS buffers Abuf/Bbuf (ushort, 128*32 each, 16B aligned).
// ---------------------------------------------------------------------------
#define GEMM_CORE(KDIM, APTR, BPTR)                                           \
  const int tid = threadIdx.x;                                                \
  const int wave = tid >> 6;                                                  \
  const int lane = tid & 63;                                                  \
  const int lo = lane & 15;                                                   \
  const int quad = lane >> 4;                                                 \
  const int m0 = blockIdx.y * 128;                                            \
  const int n0 = blockIdx.x * 128;                                            \
  const int mw = (wave & 1) * 64;                                             \
  const int nw = (wave >> 1) * 64;                                            \
  f32x4 acc[4][4];                                                            \
  _Pragma("unroll") for (int i = 0; i < 4; ++i)                               \
      _Pragma("unroll") for (int j = 0; j < 4; ++j)                           \
          acc[i][j] = {0.f, 0.f, 0.f, 0.f};                                   \
  for (int kt = 0; kt < (KDIM); kt += 32) {                                   \
    _Pragma("unroll") for (int j = 0; j < 2; ++j) {                           \
      const int c = wave * 128 + j * 64 + lane;                               \
      const int row = c >> 2;                                                 \
      const int colb = (c & 3) << 4;                                          \
      const int ldsOff = (wave * 128 + j * 64) * 16;                          \
      load_lds16((const char*)(APTR) + ((size_t)(m0 + row) * (KDIM) + kt) * 2 + colb, \
                 (char*)Abuf + ldsOff);                                       \
      load_lds16((const char*)(BPTR) + ((size_t)(n0 + row) * (KDIM) + kt) * 2 + colb, \
                 (char*)Bbuf + ldsOff);                                       \
    }                                                                         \
    __syncthreads();                                                          \
    short8 af[4], bfr[4];                                                     \
    _Pragma("unroll") for (int mt = 0; mt < 4; ++mt)                          \
        af[mt] = *(const short8*)&Abuf[(mw + mt * 16 + lo) * 32 + quad * 8];  \
    _Pragma("unroll") for (int nt = 0; nt < 4; ++nt)                          \
        bfr[nt] = *(const short8*)&Bbuf[(nw + nt * 16 + lo) * 32 + quad * 8]; \
    _Pragma("unroll") for (int mt = 0; mt < 4; ++mt)                          \
        _Pragma("unroll") for (int nt = 0; nt < 4; ++nt)                      \
            acc[mt][nt] = __builtin_amdgcn_mfma_f32_16x16x32_bf16(            \
                af[mt], bfr[nt], acc[mt][nt], 0, 0, 0);                       \
    __syncthreads();                                                          \
  }

// Plain fp32-out GEMM (used for W_o)
__global__ __launch_bounds__(256) void gemm_bf16(
    const ushort* __restrict__ A, const ushort* __restrict__ Bt,
    float* __restrict__ C, int N, int K) {
  __shared__ ushort Abuf[128 * 32];
  __shared__ ushort Bbuf[128 * 32];
  GEMM_CORE(K, A, Bt)
#pragma unroll
  for (int mt = 0; mt < 4; ++mt) {
    const int r0 = m0 + mw + mt * 16 + quad * 4;
#pragma unroll
    for (int nt = 0; nt < 4; ++nt) {
      const int cc = n0 + nw + nt * 16 + lo;
#pragma unroll
      for (int r = 0; r < 4; ++r)
        C[(size_t)(r0 + r) * N + cc] = acc[mt][nt][r];
    }
  }
}

// ---------------------------------------------------------------------------
// Unified projection GEMM (PROVEN R0 baseline): A[8192][1536] @ Wall^T.
// ---------------------------------------------------------------------------
__global__ __launch_bounds__(256) void gemm_proj(
    const ushort* __restrict__ A, const ushort* __restrict__ Wall,
    ushort* __restrict__ q_bf, ushort* __restrict__ k_bf,
    ushort* __restrict__ v_bf, float* __restrict__ kg,
    float* __restrict__ vg, const float* __restrict__ cosf,
    const float* __restrict__ sinf, const int* __restrict__ pid) {
  __shared__ char smem[25088];
  ushort* Abuf = (ushort*)smem;
  ushort* Bbuf = (ushort*)(smem + 8192);
  unsigned int* CoefS = (unsigned int*)smem;      // [128][48] packed cos|sin
  int* PidS = (int*)(smem + 24576);               // [128]

  GEMM_CORE(DMODEL, A, Wall)

  // Section routing (block-uniform)
  const int xb = blockIdx.x;
  int sec, cbase;
  if (xb < 12)      { sec = 0; cbase = 0; }
  else if (xb < 15) { sec = 1; cbase = 1536; }
  else if (xb < 18) { sec = 2; cbase = 1920; }
  else if (xb < 21) { sec = 3; cbase = 2304; }
  else              { sec = 4; cbase = 2688; }
  const bool doRope = (sec == 0) || (sec == 1) || (sec == 3);

  if (tid < 128) PidS[tid] = pid[m0 + tid];
  __syncthreads();
  if (doRope) {
#pragma unroll
    for (int j = 0; j < 24; ++j) {
      const int idx = j * 256 + tid;          // 0..6143
      const int rr = idx / 48;
      const int ff = idx - rr * 48;
      const int pos = PidS[rr];
      const float c = cosf[(size_t)pos * NFREQ + ff];
      const float s = sinf[(size_t)pos * NFREQ + ff];
      CoefS[idx] = (unsigned int)f2bf(c) | ((unsigned int)f2bf(s) << 16);
    }
  }
  __syncthreads();

#pragma unroll
  for (int mt = 0; mt < 4; ++mt) {
    const int lr0 = mw + mt * 16 + quad * 4;   // local row 0..127
#pragma unroll
    for (int nt = 0; nt < 4; ++nt) {
      const int cc = n0 + nw + nt * 16 + lo;
      const int col = cc - cbase;
      const int d = col % HD;
      const int fi = d >> 1;
#pragma unroll
      for (int r = 0; r < 4; ++r) {
        const int lr = lr0 + r;
        float v = acc[mt][nt][r];
        if (doRope) {
          const unsigned int pk = CoefS[lr * 48 + fi];
          const float co = bf2f((ushort)(pk & 0xFFFF));
          const float si = bf2f((ushort)(pk >> 16));
          const float pe = __shfl_xor(v, 1);
          v = (d & 1) ? fmaf(pe, si, v * co) : fmaf(v, co, -pe * si);
        }
        const int t = m0 + lr;
        if (sec == 0)      q_bf[(size_t)t * DMODEL + col] = f2bf(v);
        else if (sec == 1) k_bf[(size_t)t * KVDIM + col] = f2bf(v);
        else if (sec == 2) v_bf[(size_t)t * KVDIM + col] = f2bf(v);
        else if (sec == 3) kg[(size_t)t * KVDIM + col] = v;
        else               vg[(size_t)t * KVDIM + col] = v;
      }
    }
  }
}

// ---------------------------------------------------------------------------
// qg row 0: zero + split-k atomics
// ---------------------------------------------------------------------------
__global__ void qg0_zero(float* __restrict__ qg0) {
  qg0[blockIdx.x * 256 + threadIdx.x] = 0.f;
}
__global__ __launch_bounds__(256) void qg0_split(
    const float* __restrict__ x, const float* __restrict__ W,
    float* __restrict__ qg0) {
  const int j = blockIdx.x * 256 + threadIdx.x;
  const int k0 = blockIdx.y * 128;
  float acc = 0.f;
#pragma unroll 8
  for (int k = k0; k < k0 + 128; ++k)
    acc = fmaf(x[k], W[(size_t)k * DMODEL + j], acc);
  atomicAdd(&qg0[j], acc);
}

// ---------------------------------------------------------------------------
// Local attention v5: GQA-shared K/V tiles. Block = 4 waves = 4 Q-heads of
// one KV group, 32 q-rows. K/V staged ONCE per block (vs once per head in
// v4), double-buffered with stage-ahead + counted vmcnt(6) (T3 minimum
// 2-phase). Q held in registers (loaded once, reused across 5 key tiles and
// for the global-token dot product).
//
// Staging: per tile, 24 x 1KB global_load_lds issues (12 K + 12 V), wave w
// issues K[w*3+j] and V[w*3+j] (wave-uniform LDS dest = issue*1024; per-lane
// global src). 6 issues/wave/tile -> WAITV(6) after staging tile t+1
// confirms tile t (FIFO).
//
// Layouts match v4: Kb [3 panels][64 rows][32 dims], Vt [2 panels][96 dims]
// [32 keys]; per-wave Pb [2 mf][2 kp][16 rows][32 keys].
// ---------------------------------------------------------------------------
__global__ __launch_bounds__(256) void local_attn_v5(
    const ushort* __restrict__ qbf, const ushort* __restrict__ kbf,
    const ushort* __restrict__ vtg, const float* __restrict__ kg,
    const float* __restrict__ vg, ushort* __restrict__ obf) {
  __shared__ ushort Kb[2][3 * 64 * 32];   // 2 x 12KB
  __shared__ ushort Vt[2][2 * 96 * 32];   // 2 x 12KB
  __shared__ ushort Pb[4][2048];          // per-wave 4KB
  __shared__ float Kg0[HD];
  __shared__ float Vg0[HD];
  __shared__ float SgS[4][32];

  // XCD-locality remap: all blocks of one kh land on one XCD pair
  // (K+V slice per kh = 3MB < 4MB L2). flat = y*256+x; dispatch ~ flat,
  // XCD ~ flat%8 -> kh = (flat&7)>>1, bx = (flat>>3)*2 + (flat&1). Bijective.
  const int flat = (int)blockIdx.y * 256 + (int)blockIdx.x;
  const int kh = (flat & 7) >> 1;
  const int bx = ((flat >> 3) << 1) + (flat & 1);   // 0..255
  const int t0 = bx * 32;
  const int tid = threadIdx.x;
  const int w = tid >> 6;             // wave = head within KV group
  const int h = kh * 4 + w;
  const int lane = tid & 63;
  const int lo   = lane & 15;
  const int quad = lane >> 4;

  // per-thread staging constants (3 K-issues + 3 V-issues per wave)
  int pK[3], rowK[3], kcK[3], kpV[3], dV[3], vcV[3];
#pragma unroll
  for (int j = 0; j < 3; ++j) {
    const int g = w * 192 + j * 64 + lane;     // 0..767
    pK[j]   = g >> 8;
    rowK[j] = (g >> 2) & 63;
    kcK[j]  = g & 3;
    kpV[j]  = (g >= 384) ? 1 : 0;
    const int rv = g - kpV[j] * 384;
    dV[j]  = rv >> 2;
    vcV[j] = rv & 3;
  }

  // Q fragments in registers (rows t0 + mf*16 + lo, dims p*32 + quad*8 ..+8)
  short8 af[2][3];
#pragma unroll
  for (int mf = 0; mf < 2; ++mf)
#pragma unroll
    for (int p = 0; p < 3; ++p)
      af[mf][p] = *(const short8*)&qbf[(size_t)(t0 + mf * 16 + lo) * DMODEL +
                                       h * HD + p * 32 + quad * 8];

  if (tid < HD) {
    Kg0[tid] = kg[kh * HD + tid];   // row 0 (rope at pos 0 = identity)
    Vg0[tid] = vg[kh * HD + tid];
  }

  f32x4 O[2][6];
#pragma unroll
  for (int mf = 0; mf < 2; ++mf)
#pragma unroll
    for (int i = 0; i < 6; ++i) O[mf][i] = {0.f, 0.f, 0.f, 0.f};
  float m_run[2][4], l_run[2][4];
#pragma unroll
  for (int mf = 0; mf < 2; ++mf)
#pragma unroll
    for (int r = 0; r < 4; ++r) { m_run[mf][r] = -1e30f; l_run[mf][r] = 0.f; }

  auto stage = [&](int ti) {
    const int kb = t0 - W2 + ti * 64;
    const int buf = ti & 1;
#pragma unroll
    for (int j = 0; j < 3; ++j) {
      int kr = kb + rowK[j];
      kr = kr < 0 ? 0 : (kr > T_LEN - 1 ? T_LEN - 1 : kr);
      load_lds16(kbf + (size_t)kr * KVDIM + kh * HD + pK[j] * 32 + kcK[j] * 8,
                 (char*)Kb[buf] + (w * 3 + j) * 1024);
    }
#pragma unroll
    for (int j = 0; j < 3; ++j) {
      int ks = kb + kpV[j] * 32 + vcV[j] * 8;
      ks = ks < 0 ? 0 : (ks > T_LEN - 8 ? T_LEN - 8 : ks);
      load_lds16(vtg + (size_t)(kh * HD + dV[j]) * T_LEN + ks,
                 (char*)Vt[buf] + (w * 3 + j) * 1024);
    }
  };

  stage(0);

  for (int ti = 0; ti < 5; ++ti) {
    const int kb = t0 - W2 + ti * 64;
    const int buf = ti & 1;
    if (ti < 4) { stage(ti + 1); WAITV(6); } else { WAITV(0); }
    SBAR();

    if (kb + 63 >= 1) {   // block-uniform: tile has at least one valid key
      // --- QK^T: both heads' halves share the K fragments ---
      f32x4 s4[2][4];
#pragma unroll
      for (int mf = 0; mf < 2; ++mf)
#pragma unroll
        for (int nt = 0; nt < 4; ++nt) s4[mf][nt] = {0.f, 0.f, 0.f, 0.f};
#pragma unroll
      for (int nt = 0; nt < 4; ++nt)
#pragma unroll
        for (int p = 0; p < 3; ++p) {
          const short8 kf =
              *(const short8*)&Kb[buf][p * 2048 + (nt * 16 + lo) * 32 + quad * 8];
          s4[0][nt] = __builtin_amdgcn_mfma_f32_16x16x32_bf16(af[0][p], kf, s4[0][nt], 0, 0, 0);
          s4[1][nt] = __builtin_amdgcn_mfma_f32_16x16x32_bf16(af[1][p], kf, s4[1][nt], 0, 0, 0);
        }

      // --- masked online softmax (per mf, per quad-row r) ---
      float alpha[2][4];
#pragma unroll
      for (int mf = 0; mf < 2; ++mf)
#pragma unroll
        for (int r = 0; r < 4; ++r) {
          const int tq = t0 + mf * 16 + quad * 4 + r;
          float sv[4], rm = -1e30f;
#pragma unroll
          for (int nt = 0; nt < 4; ++nt) {
            const int p = kb + nt * 16 + lo;
            const bool ok = (p >= 1) && (p <= tq) && (p + W2 >= tq);
            sv[nt] = ok ? s4[mf][nt][r] * SCALE : -1e30f;
            rm = fmaxf(rm, sv[nt]);
          }
#pragma unroll
          for (int mo = 1; mo < 16; mo <<= 1) rm = fmaxf(rm, __shfl_xor(rm, mo));
          const float m_new = fmaxf(m_run[mf][r], rm);
          float psum = 0.f;
#pragma unroll
          for (int nt = 0; nt < 4; ++nt) {
            const float pv = (sv[nt] > -1e29f) ? __expf(sv[nt] - m_new) : 0.f;
            Pb[w][mf * 1024 + (nt >> 1) * 512 + (quad * 4 + r) * 32 +
                  (nt & 1) * 16 + lo] = f2bf(pv);
            psum += pv;
          }
#pragma unroll
          for (int mo = 1; mo < 16; mo <<= 1) psum += __shfl_xor(psum, mo);
          alpha[mf][r] = __expf(m_run[mf][r] - m_new);
          l_run[mf][r] = l_run[mf][r] * alpha[mf][r] + psum;
          m_run[mf][r] = m_new;
        }

#pragma unroll
      for (int mf = 0; mf < 2; ++mf)
#pragma unroll
        for (int nt6 = 0; nt6 < 6; ++nt6)
#pragma unroll
          for (int r = 0; r < 4; ++r) O[mf][nt6][r] *= alpha[mf][r];

      // --- PV: both mf share the V fragments ---
      short8 pa[2][2];
#pragma unroll
      for (int mf = 0; mf < 2; ++mf)
#pragma unroll
        for (int kp = 0; kp < 2; ++kp)
          pa[mf][kp] =
              *(const short8*)&Pb[w][mf * 1024 + kp * 512 + lo * 32 + quad * 8];
#pragma unroll
      for (int nt6 = 0; nt6 < 6; ++nt6)
#pragma unroll
        for (int kp = 0; kp < 2; ++kp) {
          const short8 vb8 =
              *(const short8*)&Vt[buf][kp * 3072 + (nt6 * 16 + lo) * 32 + quad * 8];
          O[0][nt6] = __builtin_amdgcn_mfma_f32_16x16x32_bf16(pa[0][kp], vb8, O[0][nt6], 0, 0, 0);
          O[1][nt6] = __builtin_amdgcn_mfma_f32_16x16x32_bf16(pa[1][kp], vb8, O[1][nt6], 0, 0, 0);
        }
    }
    SBAR();
  }

  // --- global token: sg = Q . Kg0 from register fragments ---
#pragma unroll
  for (int mf = 0; mf < 2; ++mf) {
    float part = 0.f;
#pragma unroll
    for (int p = 0; p < 3; ++p)
#pragma unroll
      for (int j = 0; j < 8; ++j)
        part += bf2f((ushort)af[mf][p][j]) * Kg0[p * 32 + quad * 8 + j];
    part += __shfl_xor(part, 16);
    part += __shfl_xor(part, 32);
    if (lane < 16) SgS[w][mf * 16 + lane] = part * SCALE;  // row mf*16+lo
  }
  asm volatile("s_waitcnt lgkmcnt(0)" ::: "memory");  // same-wave LDS RAW

#pragma unroll
  for (int mf = 0; mf < 2; ++mf)
#pragma unroll
    for (int r = 0; r < 4; ++r) {
      const float sgv = SgS[w][mf * 16 + quad * 4 + r];
      const float m_new = fmaxf(m_run[mf][r], sgv);
      const float al = __expf(m_run[mf][r] - m_new);
      const float pg = __expf(sgv - m_new);
      const float inv = 1.0f / (l_run[mf][r] * al + pg);
      ushort* dst =
          obf + (size_t)(t0 + mf * 16 + quad * 4 + r) * DMODEL + h * HD;
#pragma unroll
      for (int nt6 = 0; nt6 < 6; ++nt6) {
        const int d = nt6 * 16 + lo;
        dst[d] = f2bf((O[mf][nt6][r] * al + pg * Vg0[d]) * inv);
      }
    }
}

// ---------------------------------------------------------------------------
// Global row, split-k partials: grid (NH, NGB); 256 keys per block.
// ---------------------------------------------------------------------------
__global__ __launch_bounds__(256) void global_attn_part(
    const float* __restrict__ qg0, const float* __restrict__ kg,
    const float* __restrict__ vg, float* __restrict__ gM,
    float* __restrict__ gL, float* __restrict__ gO) {
  const int h = blockIdx.x;
  const int g = blockIdx.y;
  const int kh = h >> 2;
  const int tid = threadIdx.x;
  const int wv = tid >> 6;
  __shared__ float q[HD];
  __shared__ float sp[256];
  __shared__ float red[4];
  __shared__ float od[2][HD];

  if (tid < HD) q[tid] = qg0[h * HD + tid];
  __syncthreads();

  const int key = g * 256 + tid;
  const float* kp = kg + (size_t)key * KVDIM + kh * HD;
  float d = 0.f;
#pragma unroll
  for (int j = 0; j < 24; ++j) {
    const f32x4 kv = *(const f32x4*)(kp + j * 4);
    const f32x4 qv = *(const f32x4*)(&q[j * 4]);
    d += qv[0] * kv[0] + qv[1] * kv[1] + qv[2] * kv[2] + qv[3] * kv[3];
  }
  d *= SCALE;

  float pm = d;
#pragma unroll
  for (int off = 32; off > 0; off >>= 1) pm = fmaxf(pm, __shfl_down(pm, off));
  if ((tid & 63) == 0) red[wv] = pm;
  __syncthreads();
  const float M = fmaxf(fmaxf(red[0], red[1]), fmaxf(red[2], red[3]));
  __syncthreads();
  const float p = __expf(d - M);
  sp[tid] = p;
  float ps = p;
#pragma unroll
  for (int off = 32; off > 0; off >>= 1) ps += __shfl_down(ps, off);
  if ((tid & 63) == 0) red[wv] = ps;
  __syncthreads();
  const float L = red[0] + red[1] + red[2] + red[3];

  if (tid < 192) {
    const int grp = tid >= HD;
    const int dd = tid - grp * HD;
    float acc = 0.f;
    const float* vp = vg + (size_t)(g * 256 + grp * 128) * KVDIM + kh * HD + dd;
#pragma unroll 4
    for (int i = 0; i < 128; ++i)
      acc = fmaf(sp[grp * 128 + i], vp[(size_t)i * KVDIM], acc);
    od[grp][dd] = acc;
  }
  __syncthreads();
  if (tid < HD) gO[((size_t)h * NGB + g) * HD + tid] = od[0][tid] + od[1][tid];
  if (tid == 0) { gM[h * NGB + g] = M; gL[h * NGB + g] = L; }
}

__global__ void global_attn_comb(const float* __restrict__ gM,
                                 const float* __restrict__ gL,
                                 const float* __restrict__ gO,
                                 ushort* __restrict__ obf) {
  const int h = blockIdx.x;
  const int d = threadIdx.x;
  if (d >= HD) return;
  float M = -1e30f;
  for (int g = 0; g < NGB; ++g) M = fmaxf(M, gM[h * NGB + g]);
  float L = 0.f, O = 0.f;
  for (int g = 0; g < NGB; ++g) {
    const float e = __expf(gM[h * NGB + g] - M);
    L += gL[h * NGB + g] * e;
    O += gO[((size_t)h * NGB + g) * HD + d] * e;
  }
  obf[h * HD + d] = f2bf(O / L);
}

// ---------------------------------------------------------------------------
// Launch
// ---------------------------------------------------------------------------
extern "C" void kernel_launch(void* const* d_in, const int* in_sizes, int n_in,
                              void* d_out, int out_size, void* d_ws, size_t ws_size,
                              hipStream_t stream) {
  const float* x     = (const float*)d_in[0];
  const float* cosf  = (const float*)d_in[1];
  const float* sinf  = (const float*)d_in[2];
  const int*   pid   = (const int*)d_in[3];
  const float* W_qs  = (const float*)d_in[4];
  const float* W_ks  = (const float*)d_in[5];
  const float* W_vs  = (const float*)d_in[6];
  const float* W_qg  = (const float*)d_in[7];
  const float* W_kg  = (const float*)d_in[8];
  const float* W_vg  = (const float*)d_in[9];
  const float* W_o   = (const float*)d_in[10];
  float* out = (float*)d_out;

  char* p = (char*)d_ws;
  auto alloc = [&](size_t bytes) { char* r = p; p += (bytes + 255) & ~(size_t)255; return r; };
  float*  kg     = (float*)alloc((size_t)T_LEN * KVDIM * 4);
  float*  vg     = (float*)alloc((size_t)T_LEN * KVDIM * 4);
  float*  qg0    = (float*)alloc(DMODEL * 4);
  ushort* x_bf   = (ushort*)alloc((size_t)T_LEN * DMODEL * 2);
  ushort* q_bf   = (ushort*)alloc((size_t)T_LEN * DMODEL * 2);
  ushort* attnbf = (ushort*)alloc((size_t)T_LEN * DMODEL * 2);
  ushort* k_bf   = (ushort*)alloc((size_t)T_LEN * KVDIM * 2);
  ushort* v_bf   = (ushort*)alloc((size_t)T_LEN * KVDIM * 2);
  ushort* vt_g   = (ushort*)alloc((size_t)KVDIM * T_LEN * 2);
  ushort* Wall   = (ushort*)alloc((size_t)NPROJ * DMODEL * 2);  // q + 4 KV
  ushort* Wo_t   = (ushort*)alloc((size_t)DMODEL * DMODEL * 2);
  float*  gM     = (float*)alloc((size_t)NH * NGB * 4);
  float*  gL     = (float*)alloc((size_t)NH * NGB * 4);
  float*  gO     = (float*)alloc((size_t)NH * NGB * HD * 4);

  const dim3 blk(256);
  const int nX4 = (T_LEN * DMODEL) / 4;

  // bf16 conversions / weight transposes (packed into Wall)
  convert_bf16<<<(nX4 + 255) / 256, blk, 0, stream>>>(x, x_bf, nX4);
  transpose_bf16<<<dim3(DMODEL / 32, DMODEL / 32), blk, 0, stream>>>(W_qs, Wall, DMODEL, DMODEL);
  transpose_bf16<<<dim3(DMODEL / 32, DMODEL / 32), blk, 0, stream>>>(W_o,  Wo_t, DMODEL, DMODEL);
  transpose_bf16_kv4<<<dim3(KVDIM / 32, DMODEL / 32, 4), blk, 0, stream>>>(
      W_ks, W_vs, W_kg, W_vg, Wall + (size_t)DMODEL * DMODEL);

  // Unified projection GEMM with fused RoPE/bf16 epilogue (R0 baseline)
  gemm_proj<<<dim3(NPROJ / 128, T_LEN / 128), blk, 0, stream>>>(
      x_bf, Wall, q_bf, k_bf, v_bf, kg, vg, cosf, sinf, pid);

  // qg row 0 (RoPE at pos 0 is identity -> skipped)
  qg0_zero<<<DMODEL / 256, blk, 0, stream>>>(qg0);
  qg0_split<<<dim3(DMODEL / 256, DMODEL / 128), blk, 0, stream>>>(x, W_qg, qg0);

  // V pre-transpose for local attention
  transpose_u16<<<dim3(KVDIM / 32, T_LEN / 32), blk, 0, stream>>>(v_bf, vt_g);

  // Attention (v5: GQA-shared K/V, 32-row q tiles, double-buffered staging)
  local_attn_v5<<<dim3(256, 4), blk, 0, stream>>>(
      q_bf, k_bf, vt_g, kg, vg, attnbf);
  global_attn_part<<<dim3(NH, NGB), blk, 0, stream>>>(qg0, kg, vg, gM, gL, gO);
  global_attn_comb<<<NH, dim3(128), 0, stream>>>(gM, gL, gO, attnbf);

  // Output projection (R0 baseline)
  gemm_bf16<<<dim3(DMODEL / 128, T_LEN / 128), blk, 0, stream>>>(
      attnbf, Wo_t, out, DMODEL, DMODEL);
}